// Round 4
// baseline (1488.902 us; speedup 1.0000x reference)
//
#include <hip/hip_runtime.h>
#include <math.h>

#define N_NODES 30000
#define N_EDGES 480000
#define HEADS   6

// ---------- bf16 helpers (RNE pack, cheap unpack) ----------
__device__ __forceinline__ unsigned short f2bf(float f) {
    unsigned u = __float_as_uint(f);
    u += 0x7fffu + ((u >> 16) & 1u);   // round-to-nearest-even
    return (unsigned short)(u >> 16);
}
__device__ __forceinline__ float bf_lo(unsigned p) { return __uint_as_float(p << 16); }
__device__ __forceinline__ float bf_hi(unsigned p) { return __uint_as_float(p & 0xffff0000u); }

// ---------- z = h @ W  (h: [N,K] f32, W: [K,HF] f32, z: [N,HF] bf16) ----------
template <int K, int HF, int TM>
__global__ void gemm_kernel(const float* __restrict__ h, const float* __restrict__ W,
                            unsigned short* __restrict__ z) {
    __shared__ float hs[TM * K];
    const int m0 = blockIdx.x * TM;
    const int j  = blockIdx.y * 64 + threadIdx.x;
    for (int idx = threadIdx.x; idx < TM * K; idx += 64) hs[idx] = h[m0 * K + idx];
    __syncthreads();
    if (j >= HF) return;
    float acc[TM];
#pragma unroll
    for (int m = 0; m < TM; ++m) acc[m] = 0.f;
    for (int k = 0; k < K; ++k) {
        float w = W[k * HF + j];
#pragma unroll
        for (int m = 0; m < TM; ++m) acc[m] = fmaf(hs[m * K + k], w, acc[m]);
    }
#pragma unroll
    for (int m = 0; m < TM; ++m) z[(size_t)(m0 + m) * HF + j] = f2bf(acc[m]);
}

// ---------- es/ed: attention logit halves per (node, head), bf16 z in ----------
template <int HF>
__global__ void prep_kernel(const unsigned short* __restrict__ z,
                            const float* __restrict__ a_s, const float* __restrict__ a_d,
                            float* __restrict__ es, float* __restrict__ ed) {
    constexpr int Fo = HF / HEADS;
    const int idx = blockIdx.x * 256 + threadIdx.x;
    if (idx >= N_NODES * HEADS) return;
    const int n = idx / HEADS;
    const int h = idx - n * HEADS;
    const unsigned* zp = (const unsigned*)(z + (size_t)n * HF + h * Fo);
    const float* as = a_s + h * Fo;
    const float* ad = a_d + h * Fo;
    float s = 0.f, d = 0.f;
#pragma unroll 8
    for (int p = 0; p < Fo / 2; ++p) {
        const unsigned zz = zp[p];
        const float z0 = bf_lo(zz), z1 = bf_hi(zz);
        s = fmaf(z0, as[2 * p], s);
        s = fmaf(z1, as[2 * p + 1], s);
        d = fmaf(z0, ad[2 * p], d);
        d = fmaf(z1, ad[2 * p + 1], d);
    }
    es[idx] = s;
    ed[idx] = d;
}

// ---------- CSR build ----------
__global__ void zero_int_kernel(int* __restrict__ p, int n) {
    const int i = blockIdx.x * 256 + threadIdx.x;
    if (i < n) p[i] = 0;
}

__global__ void hist_kernel(const int* __restrict__ ei, int* __restrict__ cnt) {
    const int e = blockIdx.x * 256 + threadIdx.x;
    if (e >= N_EDGES) return;
    atomicAdd(&cnt[ei[N_EDGES + e]], 1);
}

__global__ void scan_kernel(const int* __restrict__ cnt, int* __restrict__ off,
                            int* __restrict__ cursor) {
    __shared__ int s[1024];
    const int t = threadIdx.x;
    int carry = 0;
    for (int base = 0; base < N_NODES; base += 1024) {
        const int idx = base + t;
        const int v = (idx < N_NODES) ? cnt[idx] : 0;
        s[t] = v;
        __syncthreads();
        for (int d = 1; d < 1024; d <<= 1) {
            int x = (t >= d) ? s[t - d] : 0;
            __syncthreads();
            s[t] += x;
            __syncthreads();
        }
        const int excl = s[t] - v;
        if (idx < N_NODES) { off[idx] = carry + excl; cursor[idx] = carry + excl; }
        const int total = s[1023];
        __syncthreads();
        carry += total;
    }
    if (t == 0) off[N_NODES] = carry;
}

__global__ void scatter_kernel(const int* __restrict__ ei, int* __restrict__ cursor,
                               int* __restrict__ csr_src, int* __restrict__ csr_dst) {
    const int e = blockIdx.x * 256 + threadIdx.x;
    if (e >= N_EDGES) return;
    const int src = ei[e];
    const int dst = ei[N_EDGES + e];
    const int slot = atomicAdd(&cursor[dst], 1);
    csr_src[slot] = src;
    csr_dst[slot] = dst;
}

// ---------- edge weights: w = exp(leaky_relu(es[src]+ed[dst])), edge-parallel ----------
__global__ void edge_w_kernel(const int* __restrict__ csr_src, const int* __restrict__ csr_dst,
                              const float* __restrict__ es, const float* __restrict__ ed,
                              float* __restrict__ w) {
    const int idx = blockIdx.x * 256 + threadIdx.x;
    if (idx >= N_EDGES * HEADS) return;
    const int i = idx / HEADS;
    const int h = idx - i * HEADS;
    const int src = csr_src[i];
    const int dst = csr_dst[i];
    float v = es[src * HEADS + h] + ed[dst * HEADS + h];
    v = v > 0.f ? v : 0.2f * v;
    w[idx] = __expf(v);
}

// ---------- fused pull aggregation: bf16 z gather + denom + ELU ----------
// one wave per (dst node, head); each lane covers 2 features (packed uint load)
template <int HF>
__global__ void agg_pull_kernel(const int* __restrict__ off, const int* __restrict__ csr_src,
                                const float* __restrict__ w,
                                const unsigned short* __restrict__ z,
                                float* __restrict__ out) {
    constexpr int Fo  = HF / HEADS;
    constexpr int L   = Fo / 2;   // lanes per edge
    constexpr int EPI = 64 / L;   // edges in parallel
    const int wid  = (blockIdx.x * blockDim.x + threadIdx.x) >> 6;
    const int lane = threadIdx.x & 63;
    if (wid >= N_NODES * HEADS) return;
    const int n = wid / HEADS;
    const int h = wid - n * HEADS;
    const int s0  = off[n];
    const int deg = off[n + 1] - s0;
    const int eo = lane / L;        // edge slot within parallel group
    const int fp = lane - eo * L;   // feature-pair index

    float acc0 = 0.f, acc1 = 0.f, l = 0.f;
#pragma unroll 2
    for (int i = eo; i < deg; i += EPI) {
        const int src = csr_src[s0 + i];
        const float ww = w[(s0 + i) * HEADS + h];   // independent of csr load
        l += ww;
        const unsigned zz =
            *(const unsigned*)(z + (size_t)src * HF + h * Fo + 2 * fp);
        acc0 = fmaf(ww, bf_lo(zz), acc0);
        acc1 = fmaf(ww, bf_hi(zz), acc1);
    }
#pragma unroll
    for (int d = L; d < 64; d <<= 1) {
        acc0 += __shfl_xor(acc0, d);
        acc1 += __shfl_xor(acc1, d);
        l    += __shfl_xor(l, d);
    }
    if (eo == 0) {
        const float inv = 1.f / (l + 1e-16f);
        float o0 = acc0 * inv, o1 = acc1 * inv;
        o0 = o0 > 0.f ? o0 : expm1f(o0);
        o1 = o1 > 0.f ? o1 : expm1f(o1);
        float* op = out + (size_t)n * HF + h * Fo + 2 * fp;
        op[0] = o0;
        op[1] = o1;
    }
}

// ---------- sum pooling ----------
__global__ void pool_kernel(const float* __restrict__ h, float* __restrict__ pooled) {
    const int ROWS = 100;
    const int c = threadIdx.x;
    const int r0 = blockIdx.x * ROWS;
    float acc = 0.f;
    for (int r = 0; r < ROWS; ++r) acc += h[(r0 + r) * 384 + c];
    atomicAdd(&pooled[c], acc);
}

__global__ void zero_pooled_kernel(float* __restrict__ p) {
    const int i = blockIdx.x * 256 + threadIdx.x;
    if (i < 768) p[i] = 0.f;
}

__global__ void final_kernel(const float* __restrict__ pooled, const float* __restrict__ Wd,
                             const float* __restrict__ bd, float* __restrict__ outp) {
    __shared__ float s_ss[256], s_dot[256];
    const int t = threadIdx.x;
    float ss = 0.f, dot = 0.f;
    for (int c = t; c < 768; c += 256) {
        const float v = pooled[c];
        ss  = fmaf(v, v, ss);
        dot = fmaf(v, Wd[c], dot);
    }
    s_ss[t] = ss; s_dot[t] = dot;
    __syncthreads();
    for (int off = 128; off > 0; off >>= 1) {
        if (t < off) { s_ss[t] += s_ss[t + off]; s_dot[t] += s_dot[t + off]; }
        __syncthreads();
    }
    if (t == 0) {
        const float norm = fmaxf(sqrtf(s_ss[0]), 1e-12f);
        outp[0] = s_dot[0] / norm + bd[0];
    }
}

// ---------- host-side layer driver ----------
template <int K, int HF>
static void run_layer(const float* h, const float* W, const float* as_, const float* ad_,
                      const int* off, const int* csr_src, const int* csr_dst,
                      unsigned short* z, float* es, float* ed, float* wbuf, float* hout,
                      hipStream_t stream) {
    constexpr int TM = 16;
    dim3 gg(N_NODES / TM, (HF + 63) / 64);
    gemm_kernel<K, HF, TM><<<gg, 64, 0, stream>>>(h, W, z);
    prep_kernel<HF><<<(N_NODES * HEADS + 255) / 256, 256, 0, stream>>>(z, as_, ad_, es, ed);
    edge_w_kernel<<<(N_EDGES * HEADS + 255) / 256, 256, 0, stream>>>(csr_src, csr_dst, es, ed,
                                                                     wbuf);
    const int waves = N_NODES * HEADS;   // one wave per (node, head)
    agg_pull_kernel<HF><<<(waves + 3) / 4, 256, 0, stream>>>(off, csr_src, wbuf, z, hout);
}

static void build_csr(const int* ei, int* cnt, int* off, int* cursor, int* csr_src,
                      int* csr_dst, hipStream_t stream) {
    zero_int_kernel<<<(N_NODES + 255) / 256, 256, 0, stream>>>(cnt, N_NODES);
    hist_kernel<<<(N_EDGES + 255) / 256, 256, 0, stream>>>(ei, cnt);
    scan_kernel<<<1, 1024, 0, stream>>>(cnt, off, cursor);
    scatter_kernel<<<(N_EDGES + 255) / 256, 256, 0, stream>>>(ei, cursor, csr_src, csr_dst);
}

extern "C" void kernel_launch(void* const* d_in, const int* in_sizes, int n_in,
                              void* d_out, int out_size, void* d_ws, size_t ws_size,
                              hipStream_t stream) {
    const float* x_int = (const float*)d_in[0];
    const float* x_nh  = (const float*)d_in[1];
    const int*   ei_int = (const int*)d_in[2];
    const int*   ei_nh  = (const int*)d_in[3];
    const float* W1  = (const float*)d_in[4];
    const float* a1s = (const float*)d_in[5];
    const float* a1d = (const float*)d_in[6];
    const float* W2  = (const float*)d_in[7];
    const float* a2s = (const float*)d_in[8];
    const float* a2d = (const float*)d_in[9];
    const float* W3  = (const float*)d_in[10];
    const float* a3s = (const float*)d_in[11];
    const float* a3d = (const float*)d_in[12];
    const float* Wd  = (const float*)d_in[13];
    const float* bd  = (const float*)d_in[14];
    float* out = (float*)d_out;

    // workspace layout
    float* ws = (float*)d_ws;
    float* ping0 = ws;                               // N*384 f32
    float* ping1 = ping0 + (size_t)N_NODES * 384;
    float* es    = ping1 + (size_t)N_NODES * 384;    // N*H
    float* ed    = es    + (size_t)N_NODES * HEADS;
    float* wbuf  = ed    + (size_t)N_NODES * HEADS;  // E*H
    float* pooled = wbuf + (size_t)N_EDGES * HEADS;  // 768
    int* cnt     = (int*)(pooled + 768);             // N
    int* off     = cnt + N_NODES;                    // N+1
    int* cursor  = off + N_NODES + 1;                // N
    int* csr_src = cursor + N_NODES;                 // E
    int* csr_dst = csr_src + N_EDGES;                // E
    unsigned short* zbuf = (unsigned short*)(csr_dst + N_EDGES);  // N*384 bf16

    zero_pooled_kernel<<<3, 256, 0, stream>>>(pooled);

    // ---- graph "int" ----
    build_csr(ei_int, cnt, off, cursor, csr_src, csr_dst, stream);
    run_layer<11, 96>(x_int, W1, a1s, a1d, off, csr_src, csr_dst, zbuf, es, ed, wbuf, ping0, stream);
    run_layer<96, 192>(ping0, W2, a2s, a2d, off, csr_src, csr_dst, zbuf, es, ed, wbuf, ping1, stream);
    run_layer<192, 384>(ping1, W3, a3s, a3d, off, csr_src, csr_dst, zbuf, es, ed, wbuf, ping0, stream);
    pool_kernel<<<N_NODES / 100, 384, 0, stream>>>(ping0, pooled);

    // ---- graph "nh" ----
    build_csr(ei_nh, cnt, off, cursor, csr_src, csr_dst, stream);
    run_layer<11, 96>(x_nh, W1, a1s, a1d, off, csr_src, csr_dst, zbuf, es, ed, wbuf, ping0, stream);
    run_layer<96, 192>(ping0, W2, a2s, a2d, off, csr_src, csr_dst, zbuf, es, ed, wbuf, ping1, stream);
    run_layer<192, 384>(ping1, W3, a3s, a3d, off, csr_src, csr_dst, zbuf, es, ed, wbuf, ping0, stream);
    pool_kernel<<<N_NODES / 100, 384, 0, stream>>>(ping0, pooled + 384);

    final_kernel<<<1, 256, 0, stream>>>(pooled, Wd, bd, out);
}

// Round 5
// 1002.391 us; speedup vs baseline: 1.4854x; 1.4854x over previous
//
#include <hip/hip_runtime.h>
#include <math.h>

#define N_NODES 30000
#define N_EDGES 480000
#define HEADS   6

typedef __attribute__((ext_vector_type(8))) short bf16x8;
typedef __attribute__((ext_vector_type(4))) float f32x4;

// ---------- bf16 helpers (RNE pack, cheap unpack) ----------
__device__ __forceinline__ unsigned short f2bf(float f) {
    unsigned u = __float_as_uint(f);
    u += 0x7fffu + ((u >> 16) & 1u);   // round-to-nearest-even
    return (unsigned short)(u >> 16);
}
__device__ __forceinline__ float bf_lo(unsigned p) { return __uint_as_float(p << 16); }
__device__ __forceinline__ float bf_hi(unsigned p) { return __uint_as_float(p & 0xffff0000u); }

// ---------- layer-1 GEMM (K=11, tiny): VALU, f32 h in, bf16 z out ----------
template <int K, int HF, int TM>
__global__ void gemm_kernel(const float* __restrict__ h, const float* __restrict__ W,
                            unsigned short* __restrict__ z) {
    __shared__ float hs[TM * K];
    const int m0 = blockIdx.x * TM;
    const int j  = blockIdx.y * 64 + threadIdx.x;
    for (int idx = threadIdx.x; idx < TM * K; idx += 64) hs[idx] = h[m0 * K + idx];
    __syncthreads();
    if (j >= HF) return;
    float acc[TM];
#pragma unroll
    for (int m = 0; m < TM; ++m) acc[m] = 0.f;
    for (int k = 0; k < K; ++k) {
        float w = W[k * HF + j];
#pragma unroll
        for (int m = 0; m < TM; ++m) acc[m] = fmaf(hs[m * K + k], w, acc[m]);
    }
#pragma unroll
    for (int m = 0; m < TM; ++m) z[(size_t)(m0 + m) * HF + j] = f2bf(acc[m]);
}

// ---------- W -> Wt (transposed, bf16). W: [K, HF] f32 -> Wt: [HF, K] bf16 ----------
__global__ void convert_wt_kernel(const float* __restrict__ W, unsigned short* __restrict__ Wt,
                                  int K, int HF) {
    const int idx = blockIdx.x * 256 + threadIdx.x;
    if (idx >= K * HF) return;
    const int k = idx / HF;
    const int n = idx - k * HF;
    Wt[n * K + k] = f2bf(W[idx]);
}

// ---------- MFMA GEMM: z[M,HF] = h[M,K] @ W  (bf16 in, bf16 out, f32 acc) ----------
// one wave per 16-row tile; A frags preloaded; B from transposed Wt[HF,K]
template <int K, int HF>
__global__ __launch_bounds__(256) void gemm_mfma_kernel(
        const unsigned short* __restrict__ hbf, const unsigned short* __restrict__ Wt,
        unsigned short* __restrict__ z) {
    constexpr int KSTEPS = K / 32;
    const int wid = blockIdx.x * 4 + (threadIdx.x >> 6);
    if (wid >= N_NODES / 16) return;
    const int lane = threadIdx.x & 63;
    const int r16  = lane & 15;     // A: m-within-tile; B: n-within-tile; C: col
    const int quad = lane >> 4;
    const int m0 = wid * 16;

    // preload A fragments: A[m = r16][k = quad*8 + j], j=0..7 (16B contiguous)
    bf16x8 afrag[KSTEPS];
    const unsigned short* ap = hbf + (size_t)(m0 + r16) * K + quad * 8;
#pragma unroll
    for (int i = 0; i < KSTEPS; ++i) afrag[i] = *(const bf16x8*)(ap + i * 32);

    const unsigned short* bp = Wt + (size_t)r16 * K + quad * 8;
    for (int t = 0; t < HF / 16; ++t) {
        f32x4 acc = {0.f, 0.f, 0.f, 0.f};
        const unsigned short* bpt = bp + (size_t)t * 16 * K;
#pragma unroll
        for (int i = 0; i < KSTEPS; ++i) {
            const bf16x8 bfrag = *(const bf16x8*)(bpt + i * 32);
            acc = __builtin_amdgcn_mfma_f32_16x16x32_bf16(afrag[i], bfrag, acc, 0, 0, 0);
        }
        // C/D layout: col = r16 (n), row = quad*4 + reg (m)
        unsigned short* zp = z + (size_t)(m0 + quad * 4) * HF + t * 16 + r16;
#pragma unroll
        for (int r = 0; r < 4; ++r) zp[(size_t)r * HF] = f2bf(acc[r]);
    }
}

// ---------- es/ed: attention logit halves per (node, head), bf16 z in ----------
template <int HF>
__global__ void prep_kernel(const unsigned short* __restrict__ z,
                            const float* __restrict__ a_s, const float* __restrict__ a_d,
                            float* __restrict__ es, float* __restrict__ ed) {
    constexpr int Fo = HF / HEADS;
    const int idx = blockIdx.x * 256 + threadIdx.x;
    if (idx >= N_NODES * HEADS) return;
    const int n = idx / HEADS;
    const int h = idx - n * HEADS;
    const unsigned* zp = (const unsigned*)(z + (size_t)n * HF + h * Fo);
    const float* as = a_s + h * Fo;
    const float* ad = a_d + h * Fo;
    float s = 0.f, d = 0.f;
#pragma unroll 8
    for (int p = 0; p < Fo / 2; ++p) {
        const unsigned zz = zp[p];
        const float z0 = bf_lo(zz), z1 = bf_hi(zz);
        s = fmaf(z0, as[2 * p], s);
        s = fmaf(z1, as[2 * p + 1], s);
        d = fmaf(z0, ad[2 * p], d);
        d = fmaf(z1, ad[2 * p + 1], d);
    }
    es[idx] = s;
    ed[idx] = d;
}

// ---------- CSR build ----------
__global__ void zero_int_kernel(int* __restrict__ p, int n) {
    const int i = blockIdx.x * 256 + threadIdx.x;
    if (i < n) p[i] = 0;
}

__global__ void hist_kernel(const int* __restrict__ ei, int* __restrict__ cnt) {
    const int e = blockIdx.x * 256 + threadIdx.x;
    if (e >= N_EDGES) return;
    atomicAdd(&cnt[ei[N_EDGES + e]], 1);
}

__global__ void scan_kernel(const int* __restrict__ cnt, int* __restrict__ off,
                            int* __restrict__ cursor) {
    __shared__ int s[1024];
    const int t = threadIdx.x;
    int carry = 0;
    for (int base = 0; base < N_NODES; base += 1024) {
        const int idx = base + t;
        const int v = (idx < N_NODES) ? cnt[idx] : 0;
        s[t] = v;
        __syncthreads();
        for (int d = 1; d < 1024; d <<= 1) {
            int x = (t >= d) ? s[t - d] : 0;
            __syncthreads();
            s[t] += x;
            __syncthreads();
        }
        const int excl = s[t] - v;
        if (idx < N_NODES) { off[idx] = carry + excl; cursor[idx] = carry + excl; }
        const int total = s[1023];
        __syncthreads();
        carry += total;
    }
    if (t == 0) off[N_NODES] = carry;
}

__global__ void scatter_kernel(const int* __restrict__ ei, int* __restrict__ cursor,
                               int* __restrict__ csr_src, int* __restrict__ csr_dst) {
    const int e = blockIdx.x * 256 + threadIdx.x;
    if (e >= N_EDGES) return;
    const int src = ei[e];
    const int dst = ei[N_EDGES + e];
    const int slot = atomicAdd(&cursor[dst], 1);
    csr_src[slot] = src;
    csr_dst[slot] = dst;
}

// ---------- edge weights: w = exp(leaky_relu(es[src]+ed[dst])), edge-parallel ----------
__global__ void edge_w_kernel(const int* __restrict__ csr_src, const int* __restrict__ csr_dst,
                              const float* __restrict__ es, const float* __restrict__ ed,
                              float* __restrict__ w) {
    const int idx = blockIdx.x * 256 + threadIdx.x;
    if (idx >= N_EDGES * HEADS) return;
    const int i = idx / HEADS;
    const int h = idx - i * HEADS;
    const int src = csr_src[i];
    const int dst = csr_dst[i];
    float v = es[src * HEADS + h] + ed[dst * HEADS + h];
    v = v > 0.f ? v : 0.2f * v;
    w[idx] = __expf(v);
}

// ---------- fused pull aggregation: bf16 z gather + denom + ELU ----------
// one wave per (dst node, head); OUT_BF16: write packed bf16 (next layer's GEMM input)
template <int HF, bool OUT_BF16>
__global__ void agg_pull_kernel(const int* __restrict__ off, const int* __restrict__ csr_src,
                                const float* __restrict__ w,
                                const unsigned short* __restrict__ z, void* __restrict__ outv) {
    constexpr int Fo  = HF / HEADS;
    constexpr int L   = Fo / 2;   // lanes per edge (2 features per lane)
    constexpr int EPI = 64 / L;   // edges in parallel
    const int wid  = (blockIdx.x * blockDim.x + threadIdx.x) >> 6;
    const int lane = threadIdx.x & 63;
    if (wid >= N_NODES * HEADS) return;
    const int n = wid / HEADS;
    const int h = wid - n * HEADS;
    const int s0  = off[n];
    const int deg = off[n + 1] - s0;
    const int eo = lane / L;
    const int fp = lane - eo * L;

    float acc0 = 0.f, acc1 = 0.f, l = 0.f;
#pragma unroll 2
    for (int i = eo; i < deg; i += EPI) {
        const int src = csr_src[s0 + i];
        const float ww = w[(s0 + i) * HEADS + h];   // independent of csr load
        l += ww;
        const unsigned zz = *(const unsigned*)(z + (size_t)src * HF + h * Fo + 2 * fp);
        acc0 = fmaf(ww, bf_lo(zz), acc0);
        acc1 = fmaf(ww, bf_hi(zz), acc1);
    }
#pragma unroll
    for (int d = L; d < 64; d <<= 1) {
        acc0 += __shfl_xor(acc0, d);
        acc1 += __shfl_xor(acc1, d);
        l    += __shfl_xor(l, d);
    }
    if (eo == 0) {
        const float inv = 1.f / (l + 1e-16f);
        float o0 = acc0 * inv, o1 = acc1 * inv;
        o0 = o0 > 0.f ? o0 : expm1f(o0);
        o1 = o1 > 0.f ? o1 : expm1f(o1);
        const size_t base = (size_t)n * HF + h * Fo + 2 * fp;
        if (OUT_BF16) {
            const unsigned p = (unsigned)f2bf(o0) | ((unsigned)f2bf(o1) << 16);
            *(unsigned*)((unsigned short*)outv + base) = p;
        } else {
            float* op = (float*)outv + base;
            op[0] = o0;
            op[1] = o1;
        }
    }
}

// ---------- sum pooling ----------
__global__ void pool_kernel(const float* __restrict__ h, float* __restrict__ pooled) {
    const int ROWS = 100;
    const int c = threadIdx.x;
    const int r0 = blockIdx.x * ROWS;
    float acc = 0.f;
    for (int r = 0; r < ROWS; ++r) acc += h[(r0 + r) * 384 + c];
    atomicAdd(&pooled[c], acc);
}

__global__ void zero_pooled_kernel(float* __restrict__ p) {
    const int i = blockIdx.x * 256 + threadIdx.x;
    if (i < 768) p[i] = 0.f;
}

__global__ void final_kernel(const float* __restrict__ pooled, const float* __restrict__ Wd,
                             const float* __restrict__ bd, float* __restrict__ outp) {
    __shared__ float s_ss[256], s_dot[256];
    const int t = threadIdx.x;
    float ss = 0.f, dot = 0.f;
    for (int c = t; c < 768; c += 256) {
        const float v = pooled[c];
        ss  = fmaf(v, v, ss);
        dot = fmaf(v, Wd[c], dot);
    }
    s_ss[t] = ss; s_dot[t] = dot;
    __syncthreads();
    for (int off = 128; off > 0; off >>= 1) {
        if (t < off) { s_ss[t] += s_ss[t + off]; s_dot[t] += s_dot[t + off]; }
        __syncthreads();
    }
    if (t == 0) {
        const float norm = fmaxf(sqrtf(s_ss[0]), 1e-12f);
        outp[0] = s_dot[0] / norm + bd[0];
    }
}

// ---------- attention stage driver ----------
template <int HF, bool OUT_BF16>
static void run_attn(const unsigned short* z, const float* as_, const float* ad_,
                     const int* off, const int* csr_src, const int* csr_dst, float* es,
                     float* ed, float* wbuf, void* hout, hipStream_t stream) {
    prep_kernel<HF><<<(N_NODES * HEADS + 255) / 256, 256, 0, stream>>>(z, as_, ad_, es, ed);
    edge_w_kernel<<<(N_EDGES * HEADS + 255) / 256, 256, 0, stream>>>(csr_src, csr_dst, es, ed,
                                                                     wbuf);
    const int waves = N_NODES * HEADS;
    agg_pull_kernel<HF, OUT_BF16><<<(waves + 3) / 4, 256, 0, stream>>>(off, csr_src, wbuf, z,
                                                                       hout);
}

static void build_csr(const int* ei, int* cnt, int* off, int* cursor, int* csr_src,
                      int* csr_dst, hipStream_t stream) {
    zero_int_kernel<<<(N_NODES + 255) / 256, 256, 0, stream>>>(cnt, N_NODES);
    hist_kernel<<<(N_EDGES + 255) / 256, 256, 0, stream>>>(ei, cnt);
    scan_kernel<<<1, 1024, 0, stream>>>(cnt, off, cursor);
    scatter_kernel<<<(N_EDGES + 255) / 256, 256, 0, stream>>>(ei, cursor, csr_src, csr_dst);
}

extern "C" void kernel_launch(void* const* d_in, const int* in_sizes, int n_in,
                              void* d_out, int out_size, void* d_ws, size_t ws_size,
                              hipStream_t stream) {
    const float* x_int = (const float*)d_in[0];
    const float* x_nh  = (const float*)d_in[1];
    const int*   ei_int = (const int*)d_in[2];
    const int*   ei_nh  = (const int*)d_in[3];
    const float* W1  = (const float*)d_in[4];
    const float* a1s = (const float*)d_in[5];
    const float* a1d = (const float*)d_in[6];
    const float* W2  = (const float*)d_in[7];
    const float* a2s = (const float*)d_in[8];
    const float* a2d = (const float*)d_in[9];
    const float* W3  = (const float*)d_in[10];
    const float* a3s = (const float*)d_in[11];
    const float* a3d = (const float*)d_in[12];
    const float* Wd  = (const float*)d_in[13];
    const float* bd  = (const float*)d_in[14];
    float* out = (float*)d_out;

    // workspace layout — bf16 buffers first (keep 256B alignment of zbuf!)
    unsigned short* zbuf  = (unsigned short*)d_ws;                 // N*384 bf16 (aligned)
    unsigned short* hbf_a = zbuf  + (size_t)N_NODES * 384;         // N*96  bf16 (layer-1 out)
    unsigned short* hbf_b = hbf_a + (size_t)N_NODES * 96;          // N*192 bf16 (layer-2 out)
    unsigned short* wt2   = hbf_b + (size_t)N_NODES * 192;         // 192*96  bf16
    unsigned short* wt3   = wt2   + (size_t)96 * 192;              // 384*192 bf16
    float* ping0 = (float*)(wt3 + (size_t)192 * 384);              // N*384 f32 (layer-3 out)
    float* es    = ping0 + (size_t)N_NODES * 384;                  // N*H
    float* ed    = es    + (size_t)N_NODES * HEADS;
    float* wbuf  = ed    + (size_t)N_NODES * HEADS;                // E*H
    float* pooled = wbuf + (size_t)N_EDGES * HEADS;                // 768
    int* cnt     = (int*)(pooled + 768);
    int* off     = cnt + N_NODES;
    int* cursor  = off + N_NODES + 1;
    int* csr_src = cursor + N_NODES;
    int* csr_dst = csr_src + N_EDGES;

    zero_pooled_kernel<<<3, 256, 0, stream>>>(pooled);
    convert_wt_kernel<<<(96 * 192 + 255) / 256, 256, 0, stream>>>(W2, wt2, 96, 192);
    convert_wt_kernel<<<(192 * 384 + 255) / 256, 256, 0, stream>>>(W3, wt3, 192, 384);

    constexpr int TM = 16;
    const int mfma_blocks = (N_NODES / 16 + 3) / 4;

    for (int g = 0; g < 2; ++g) {
        const float* x  = g ? x_nh : x_int;
        const int*   ei = g ? ei_nh : ei_int;
        build_csr(ei, cnt, off, cursor, csr_src, csr_dst, stream);
        // layer 1: VALU GEMM (K=11)
        gemm_kernel<11, 96, TM><<<dim3(N_NODES / TM, 2), 64, 0, stream>>>(x, W1, zbuf);
        run_attn<96, true>(zbuf, a1s, a1d, off, csr_src, csr_dst, es, ed, wbuf, hbf_a, stream);
        // layer 2: MFMA GEMM
        gemm_mfma_kernel<96, 192><<<mfma_blocks, 256, 0, stream>>>(hbf_a, wt2, zbuf);
        run_attn<192, true>(zbuf, a2s, a2d, off, csr_src, csr_dst, es, ed, wbuf, hbf_b, stream);
        // layer 3: MFMA GEMM
        gemm_mfma_kernel<192, 384><<<mfma_blocks, 256, 0, stream>>>(hbf_b, wt3, zbuf);
        run_attn<384, false>(zbuf, a3s, a3d, off, csr_src, csr_dst, es, ed, wbuf, ping0, stream);
        pool_kernel<<<N_NODES / 100, 384, 0, stream>>>(ping0, pooled + g * 384);
    }

    final_kernel<<<1, 256, 0, stream>>>(pooled, Wd, bd, out);
}

// Round 6
// 916.692 us; speedup vs baseline: 1.6242x; 1.0935x over previous
//
#include <hip/hip_runtime.h>
#include <math.h>

#define N_NODES 30000
#define N_EDGES 480000
#define HEADS   6

typedef __attribute__((ext_vector_type(8))) short bf16x8;
typedef __attribute__((ext_vector_type(4))) float f32x4;

// ---------- bf16 helpers (RNE pack, cheap unpack) ----------
__device__ __forceinline__ unsigned short f2bf(float f) {
    unsigned u = __float_as_uint(f);
    u += 0x7fffu + ((u >> 16) & 1u);   // round-to-nearest-even
    return (unsigned short)(u >> 16);
}
__device__ __forceinline__ float bf_lo(unsigned p) { return __uint_as_float(p << 16); }
__device__ __forceinline__ float bf_hi(unsigned p) { return __uint_as_float(p & 0xffff0000u); }

// ---------- layer-1 GEMM (K=11, tiny): VALU, f32 h in, bf16 z out ----------
template <int K, int HF, int TM>
__global__ void gemm_kernel(const float* __restrict__ h, const float* __restrict__ W,
                            unsigned short* __restrict__ z) {
    __shared__ float hs[TM * K];
    const int m0 = blockIdx.x * TM;
    const int j  = blockIdx.y * 64 + threadIdx.x;
    for (int idx = threadIdx.x; idx < TM * K; idx += 64) hs[idx] = h[m0 * K + idx];
    __syncthreads();
    if (j >= HF) return;
    float acc[TM];
#pragma unroll
    for (int m = 0; m < TM; ++m) acc[m] = 0.f;
    for (int k = 0; k < K; ++k) {
        float w = W[k * HF + j];
#pragma unroll
        for (int m = 0; m < TM; ++m) acc[m] = fmaf(hs[m * K + k], w, acc[m]);
    }
#pragma unroll
    for (int m = 0; m < TM; ++m) z[(size_t)(m0 + m) * HF + j] = f2bf(acc[m]);
}

// ---------- W -> Wt (transposed, bf16). W: [K, HF] f32 -> Wt: [HF, K] bf16 ----------
__global__ void convert_wt_kernel(const float* __restrict__ W, unsigned short* __restrict__ Wt,
                                  int K, int HF) {
    const int idx = blockIdx.x * 256 + threadIdx.x;
    if (idx >= K * HF) return;
    const int k = idx / HF;
    const int n = idx - k * HF;
    Wt[n * K + k] = f2bf(W[idx]);
}

// ---------- MFMA GEMM: z[M,HF] = h[M,K] @ W  (bf16 in, bf16 out, f32 acc) ----------
template <int K, int HF>
__global__ __launch_bounds__(256) void gemm_mfma_kernel(
        const unsigned short* __restrict__ hbf, const unsigned short* __restrict__ Wt,
        unsigned short* __restrict__ z) {
    constexpr int KSTEPS = K / 32;
    const int wid = blockIdx.x * 4 + (threadIdx.x >> 6);
    if (wid >= N_NODES / 16) return;
    const int lane = threadIdx.x & 63;
    const int r16  = lane & 15;
    const int quad = lane >> 4;
    const int m0 = wid * 16;

    bf16x8 afrag[KSTEPS];
    const unsigned short* ap = hbf + (size_t)(m0 + r16) * K + quad * 8;
#pragma unroll
    for (int i = 0; i < KSTEPS; ++i) afrag[i] = *(const bf16x8*)(ap + i * 32);

    const unsigned short* bp = Wt + (size_t)r16 * K + quad * 8;
    for (int t = 0; t < HF / 16; ++t) {
        f32x4 acc = {0.f, 0.f, 0.f, 0.f};
        const unsigned short* bpt = bp + (size_t)t * 16 * K;
#pragma unroll
        for (int i = 0; i < KSTEPS; ++i) {
            const bf16x8 bfrag = *(const bf16x8*)(bpt + i * 32);
            acc = __builtin_amdgcn_mfma_f32_16x16x32_bf16(afrag[i], bfrag, acc, 0, 0, 0);
        }
        // C/D layout: col = r16 (n), row = quad*4 + reg (m)
        unsigned short* zp = z + (size_t)(m0 + quad * 4) * HF + t * 16 + r16;
#pragma unroll
        for (int r = 0; r < 4; ++r) zp[(size_t)r * HF] = f2bf(acc[r]);
    }
}

// ---------- es/ed: attention logit halves per (node, head), bf16 z in ----------
template <int HF>
__global__ void prep_kernel(const unsigned short* __restrict__ z,
                            const float* __restrict__ a_s, const float* __restrict__ a_d,
                            float* __restrict__ es, float* __restrict__ ed) {
    constexpr int Fo = HF / HEADS;
    const int idx = blockIdx.x * 256 + threadIdx.x;
    if (idx >= N_NODES * HEADS) return;
    const int n = idx / HEADS;
    const int h = idx - n * HEADS;
    const unsigned* zp = (const unsigned*)(z + (size_t)n * HF + h * Fo);
    const float* as = a_s + h * Fo;
    const float* ad = a_d + h * Fo;
    float s = 0.f, d = 0.f;
#pragma unroll 8
    for (int p = 0; p < Fo / 2; ++p) {
        const unsigned zz = zp[p];
        const float z0 = bf_lo(zz), z1 = bf_hi(zz);
        s = fmaf(z0, as[2 * p], s);
        s = fmaf(z1, as[2 * p + 1], s);
        d = fmaf(z0, ad[2 * p], d);
        d = fmaf(z1, ad[2 * p + 1], d);
    }
    es[idx] = s;
    ed[idx] = d;
}

// ---------- CSR build ----------
__global__ void zero_int_kernel(int* __restrict__ p, int n) {
    const int i = blockIdx.x * 256 + threadIdx.x;
    if (i < n) p[i] = 0;
}

__global__ void hist_kernel(const int* __restrict__ ei, int* __restrict__ cnt) {
    const int e = blockIdx.x * 256 + threadIdx.x;
    if (e >= N_EDGES) return;
    atomicAdd(&cnt[ei[N_EDGES + e]], 1);
}

// multi-block exclusive scan: 30 blocks x 1024
#define SCAN_NB ((N_NODES + 1023) / 1024)
__global__ void scan1_kernel(const int* __restrict__ cnt, int* __restrict__ part,
                             int* __restrict__ bsum) {
    __shared__ int s[1024];
    const int t = threadIdx.x;
    const int gid = blockIdx.x * 1024 + t;
    const int v = (gid < N_NODES) ? cnt[gid] : 0;
    s[t] = v;
    __syncthreads();
    for (int d = 1; d < 1024; d <<= 1) {
        int x = (t >= d) ? s[t - d] : 0;
        __syncthreads();
        s[t] += x;
        __syncthreads();
    }
    part[gid] = s[t] - v;   // exclusive within block
    if (t == 1023) bsum[blockIdx.x] = s[1023];
}

__global__ void scan2_kernel(int* __restrict__ bsum, int* __restrict__ boff) {
    if (threadIdx.x == 0) {
        int a = 0;
        for (int i = 0; i < SCAN_NB; ++i) { boff[i] = a; a += bsum[i]; }
        boff[SCAN_NB] = a;
    }
}

__global__ void scan3_kernel(const int* __restrict__ part, const int* __restrict__ boff,
                             int* __restrict__ off, int* __restrict__ cursor) {
    const int gid = blockIdx.x * 1024 + threadIdx.x;
    if (gid < N_NODES) {
        const int o = part[gid] + boff[gid >> 10];
        off[gid] = o;
        cursor[gid] = o;
    }
    if (gid == 0) off[N_NODES] = boff[SCAN_NB];
}

__global__ void scatter_kernel(const int* __restrict__ ei, int* __restrict__ cursor,
                               int* __restrict__ csr_src) {
    const int e = blockIdx.x * 256 + threadIdx.x;
    if (e >= N_EDGES) return;
    const int src = ei[e];
    const int dst = ei[N_EDGES + e];
    const int slot = atomicAdd(&cursor[dst], 1);
    csr_src[slot] = src;
}

// ---------- fused aggregation: edge weights + weighted gather + denom + ELU ----------
// one wave per (dst node, head). Two-phase chunk loop:
//   A: 64 lanes edge-parallel compute w = exp(leaky(es[src]+ed[n])) (coalesced csr read)
//   B: shfl-broadcast (src, w) to feature lanes; gather z, FMA.
template <int HF, bool OUT_BF16>
__global__ void agg_fused_kernel(const int* __restrict__ off, const int* __restrict__ csr_src,
                                 const float* __restrict__ es, const float* __restrict__ ed,
                                 const unsigned short* __restrict__ z, void* __restrict__ outv) {
    constexpr int Fo  = HF / HEADS;
    constexpr int L   = Fo / 2;   // lanes per edge (2 features per lane)
    constexpr int EPI = 64 / L;   // edges in parallel in phase B
    const int wid  = (blockIdx.x * blockDim.x + threadIdx.x) >> 6;
    const int lane = threadIdx.x & 63;
    if (wid >= N_NODES * HEADS) return;
    const int n = wid / HEADS;
    const int h = wid - n * HEADS;
    const int s0  = off[n];
    const int deg = off[n + 1] - s0;
    const float edn = ed[n * HEADS + h];
    const int eo = lane / L;
    const int fp = lane - eo * L;

    float acc0 = 0.f, acc1 = 0.f, lsum = 0.f;
    for (int base = 0; base < deg; base += 64) {
        const int cnt = min(64, deg - base);
        // phase A (edge-parallel across all 64 lanes)
        int my_src = 0;
        float my_w = 0.f;
        if (lane < cnt) {
            my_src = csr_src[s0 + base + lane];
            float v = es[my_src * HEADS + h] + edn;
            v = v > 0.f ? v : 0.2f * v;
            my_w = __expf(v);
        }
        // phase B (EPI edges per sub-iteration; uniform loop, predicated body)
        for (int j = 0; j < cnt; j += EPI) {
            const int jj = j + eo;
            const int   srcj = __shfl(my_src, jj);
            const float wj   = __shfl(my_w, jj);
            if (jj < cnt) {
                lsum += wj;
                const unsigned zz =
                    *(const unsigned*)(z + (size_t)srcj * HF + h * Fo + 2 * fp);
                acc0 = fmaf(wj, bf_lo(zz), acc0);
                acc1 = fmaf(wj, bf_hi(zz), acc1);
            }
        }
    }
#pragma unroll
    for (int d = L; d < 64; d <<= 1) {
        acc0 += __shfl_xor(acc0, d);
        acc1 += __shfl_xor(acc1, d);
        lsum += __shfl_xor(lsum, d);
    }
    if (eo == 0) {
        const float inv = 1.f / (lsum + 1e-16f);
        float o0 = acc0 * inv, o1 = acc1 * inv;
        o0 = o0 > 0.f ? o0 : expm1f(o0);
        o1 = o1 > 0.f ? o1 : expm1f(o1);
        const size_t basei = (size_t)n * HF + h * Fo + 2 * fp;
        if (OUT_BF16) {
            const unsigned p = (unsigned)f2bf(o0) | ((unsigned)f2bf(o1) << 16);
            *(unsigned*)((unsigned short*)outv + basei) = p;
        } else {
            float* op = (float*)outv + basei;
            op[0] = o0;
            op[1] = o1;
        }
    }
}

// ---------- sum pooling ----------
__global__ void pool_kernel(const float* __restrict__ h, float* __restrict__ pooled) {
    const int ROWS = 100;
    const int c = threadIdx.x;
    const int r0 = blockIdx.x * ROWS;
    float acc = 0.f;
    for (int r = 0; r < ROWS; ++r) acc += h[(r0 + r) * 384 + c];
    atomicAdd(&pooled[c], acc);
}

__global__ void zero_pooled_kernel(float* __restrict__ p) {
    const int i = blockIdx.x * 256 + threadIdx.x;
    if (i < 768) p[i] = 0.f;
}

__global__ void final_kernel(const float* __restrict__ pooled, const float* __restrict__ Wd,
                             const float* __restrict__ bd, float* __restrict__ outp) {
    __shared__ float s_ss[256], s_dot[256];
    const int t = threadIdx.x;
    float ss = 0.f, dot = 0.f;
    for (int c = t; c < 768; c += 256) {
        const float v = pooled[c];
        ss  = fmaf(v, v, ss);
        dot = fmaf(v, Wd[c], dot);
    }
    s_ss[t] = ss; s_dot[t] = dot;
    __syncthreads();
    for (int off = 128; off > 0; off >>= 1) {
        if (t < off) { s_ss[t] += s_ss[t + off]; s_dot[t] += s_dot[t + off]; }
        __syncthreads();
    }
    if (t == 0) {
        const float norm = fmaxf(sqrtf(s_ss[0]), 1e-12f);
        outp[0] = s_dot[0] / norm + bd[0];
    }
}

// ---------- attention stage driver ----------
template <int HF, bool OUT_BF16>
static void run_attn(const unsigned short* z, const float* as_, const float* ad_,
                     const int* off, const int* csr_src, float* es, float* ed, void* hout,
                     hipStream_t stream) {
    prep_kernel<HF><<<(N_NODES * HEADS + 255) / 256, 256, 0, stream>>>(z, as_, ad_, es, ed);
    const int waves = N_NODES * HEADS;
    agg_fused_kernel<HF, OUT_BF16><<<(waves + 3) / 4, 256, 0, stream>>>(off, csr_src, es, ed,
                                                                        z, hout);
}

static void build_csr(const int* ei, int* cnt, int* part, int* bsum, int* boff, int* off,
                      int* cursor, int* csr_src, hipStream_t stream) {
    zero_int_kernel<<<(N_NODES + 255) / 256, 256, 0, stream>>>(cnt, N_NODES);
    hist_kernel<<<(N_EDGES + 255) / 256, 256, 0, stream>>>(ei, cnt);
    scan1_kernel<<<SCAN_NB, 1024, 0, stream>>>(cnt, part, bsum);
    scan2_kernel<<<1, 64, 0, stream>>>(bsum, boff);
    scan3_kernel<<<SCAN_NB, 1024, 0, stream>>>(part, boff, off, cursor);
    scatter_kernel<<<(N_EDGES + 255) / 256, 256, 0, stream>>>(ei, cursor, csr_src);
}

extern "C" void kernel_launch(void* const* d_in, const int* in_sizes, int n_in,
                              void* d_out, int out_size, void* d_ws, size_t ws_size,
                              hipStream_t stream) {
    const float* x_int = (const float*)d_in[0];
    const float* x_nh  = (const float*)d_in[1];
    const int*   ei_int = (const int*)d_in[2];
    const int*   ei_nh  = (const int*)d_in[3];
    const float* W1  = (const float*)d_in[4];
    const float* a1s = (const float*)d_in[5];
    const float* a1d = (const float*)d_in[6];
    const float* W2  = (const float*)d_in[7];
    const float* a2s = (const float*)d_in[8];
    const float* a2d = (const float*)d_in[9];
    const float* W3  = (const float*)d_in[10];
    const float* a3s = (const float*)d_in[11];
    const float* a3d = (const float*)d_in[12];
    const float* Wd  = (const float*)d_in[13];
    const float* bd  = (const float*)d_in[14];
    float* out = (float*)d_out;

    // workspace layout — bf16 buffers first (zbuf 256B-aligned at base)
    unsigned short* zbuf  = (unsigned short*)d_ws;                 // N*384 bf16
    unsigned short* hbf_a = zbuf  + (size_t)N_NODES * 384;         // N*96  bf16
    unsigned short* hbf_b = hbf_a + (size_t)N_NODES * 96;          // N*192 bf16
    unsigned short* wt2   = hbf_b + (size_t)N_NODES * 192;         // 192*96
    unsigned short* wt3   = wt2   + (size_t)96 * 192;              // 384*192
    float* ping0 = (float*)(wt3 + (size_t)192 * 384);              // N*384 f32
    float* es    = ping0 + (size_t)N_NODES * 384;                  // N*H
    float* ed    = es    + (size_t)N_NODES * HEADS;
    float* pooled = ed   + (size_t)N_NODES * HEADS;                // 768
    int* cnt     = (int*)(pooled + 768);                           // N
    int* part    = cnt + N_NODES;                                  // SCAN_NB*1024
    int* bsum    = part + SCAN_NB * 1024;                          // SCAN_NB
    int* boff    = bsum + SCAN_NB;                                 // SCAN_NB+1
    int* off     = boff + SCAN_NB + 1;                             // N+1
    int* cursor  = off + N_NODES + 1;                              // N
    int* csr_src = cursor + N_NODES;                               // E

    zero_pooled_kernel<<<3, 256, 0, stream>>>(pooled);
    convert_wt_kernel<<<(96 * 192 + 255) / 256, 256, 0, stream>>>(W2, wt2, 96, 192);
    convert_wt_kernel<<<(192 * 384 + 255) / 256, 256, 0, stream>>>(W3, wt3, 192, 384);

    constexpr int TM = 16;
    const int mfma_blocks = (N_NODES / 16 + 3) / 4;

    for (int g = 0; g < 2; ++g) {
        const float* x  = g ? x_nh : x_int;
        const int*   ei = g ? ei_nh : ei_int;
        build_csr(ei, cnt, part, bsum, boff, off, cursor, csr_src, stream);
        gemm_kernel<11, 96, TM><<<dim3(N_NODES / TM, 2), 64, 0, stream>>>(x, W1, zbuf);
        run_attn<96, true>(zbuf, a1s, a1d, off, csr_src, es, ed, hbf_a, stream);
        gemm_mfma_kernel<96, 192><<<mfma_blocks, 256, 0, stream>>>(hbf_a, wt2, zbuf);
        run_attn<192, true>(zbuf, a2s, a2d, off, csr_src, es, ed, hbf_b, stream);
        gemm_mfma_kernel<192, 384><<<mfma_blocks, 256, 0, stream>>>(hbf_b, wt3, zbuf);
        run_attn<384, false>(zbuf, a3s, a3d, off, csr_src, es, ed, ping0, stream);
        pool_kernel<<<N_NODES / 100, 384, 0, stream>>>(ping0, pooled + g * 384);
    }

    final_kernel<<<1, 256, 0, stream>>>(pooled, Wd, bd, out);
}

// Round 7
// 876.600 us; speedup vs baseline: 1.6985x; 1.0457x over previous
//
#include <hip/hip_runtime.h>
#include <math.h>

#define N_NODES 30000
#define N_EDGES 480000
#define HEADS   6
#define NN2 (2 * N_NODES)
#define NE2 (2 * N_EDGES)

typedef __attribute__((ext_vector_type(8))) short bf16x8;
typedef __attribute__((ext_vector_type(4))) float f32x4;

// ---------- bf16 helpers ----------
__device__ __forceinline__ unsigned short f2bf(float f) {
    unsigned u = __float_as_uint(f);
    u += 0x7fffu + ((u >> 16) & 1u);   // RNE
    return (unsigned short)(u >> 16);
}
__device__ __forceinline__ float bf_lo(unsigned p) { return __uint_as_float(p << 16); }
__device__ __forceinline__ float bf_hi(unsigned p) { return __uint_as_float(p & 0xffff0000u); }

// ---------- layer-1 GEMM (K=11): VALU, both graphs batched ----------
template <int K, int HF, int TM>
__global__ void gemm1_kernel(const float* __restrict__ x0, const float* __restrict__ x1,
                             const float* __restrict__ W, unsigned short* __restrict__ z) {
    __shared__ float hs[TM * K];
    const int m0 = blockIdx.x * TM;   // global row tile (tiles never straddle N_NODES)
    const float* h = (m0 < N_NODES) ? (x0 + (size_t)m0 * K)
                                    : (x1 + (size_t)(m0 - N_NODES) * K);
    const int j = blockIdx.y * 64 + threadIdx.x;
    for (int idx = threadIdx.x; idx < TM * K; idx += 64) hs[idx] = h[idx];
    __syncthreads();
    if (j >= HF) return;
    float acc[TM];
#pragma unroll
    for (int m = 0; m < TM; ++m) acc[m] = 0.f;
    for (int k = 0; k < K; ++k) {
        float w = W[k * HF + j];
#pragma unroll
        for (int m = 0; m < TM; ++m) acc[m] = fmaf(hs[m * K + k], w, acc[m]);
    }
#pragma unroll
    for (int m = 0; m < TM; ++m) z[(size_t)(m0 + m) * HF + j] = f2bf(acc[m]);
}

// ---------- W -> Wt (transposed, bf16) ----------
__global__ void convert_wt_kernel(const float* __restrict__ W, unsigned short* __restrict__ Wt,
                                  int K, int HF) {
    const int idx = blockIdx.x * 256 + threadIdx.x;
    if (idx >= K * HF) return;
    const int k = idx / HF;
    const int n = idx - k * HF;
    Wt[n * K + k] = f2bf(W[idx]);
}

// ---------- MFMA GEMM over 2N rows ----------
template <int K, int HF>
__global__ __launch_bounds__(256) void gemm_mfma_kernel(
        const unsigned short* __restrict__ hbf, const unsigned short* __restrict__ Wt,
        unsigned short* __restrict__ z) {
    constexpr int KSTEPS = K / 32;
    const int wid = blockIdx.x * 4 + (threadIdx.x >> 6);
    if (wid >= NN2 / 16) return;
    const int lane = threadIdx.x & 63;
    const int r16  = lane & 15;
    const int quad = lane >> 4;
    const int m0 = wid * 16;

    bf16x8 afrag[KSTEPS];
    const unsigned short* ap = hbf + (size_t)(m0 + r16) * K + quad * 8;
#pragma unroll
    for (int i = 0; i < KSTEPS; ++i) afrag[i] = *(const bf16x8*)(ap + i * 32);

    const unsigned short* bp = Wt + (size_t)r16 * K + quad * 8;
    for (int t = 0; t < HF / 16; ++t) {
        f32x4 acc = {0.f, 0.f, 0.f, 0.f};
        const unsigned short* bpt = bp + (size_t)t * 16 * K;
#pragma unroll
        for (int i = 0; i < KSTEPS; ++i) {
            const bf16x8 bfrag = *(const bf16x8*)(bpt + i * 32);
            acc = __builtin_amdgcn_mfma_f32_16x16x32_bf16(afrag[i], bfrag, acc, 0, 0, 0);
        }
        // C/D layout: col = r16 (n), row = quad*4 + reg (m)
        unsigned short* zp = z + (size_t)(m0 + quad * 4) * HF + t * 16 + r16;
#pragma unroll
        for (int r = 0; r < 4; ++r) zp[(size_t)r * HF] = f2bf(acc[r]);
    }
}

// ---------- es/ed per (node, head), batched ----------
template <int HF>
__global__ void prep_kernel(const unsigned short* __restrict__ z,
                            const float* __restrict__ a_s, const float* __restrict__ a_d,
                            float* __restrict__ es, float* __restrict__ ed) {
    constexpr int Fo = HF / HEADS;
    const int idx = blockIdx.x * 256 + threadIdx.x;
    if (idx >= NN2 * HEADS) return;
    const int n = idx / HEADS;
    const int h = idx - n * HEADS;
    const unsigned* zp = (const unsigned*)(z + (size_t)n * HF + h * Fo);
    const float* as = a_s + h * Fo;
    const float* ad = a_d + h * Fo;
    float s = 0.f, d = 0.f;
#pragma unroll 8
    for (int p = 0; p < Fo / 2; ++p) {
        const unsigned zz = zp[p];
        const float z0 = bf_lo(zz), z1 = bf_hi(zz);
        s = fmaf(z0, as[2 * p], s);
        s = fmaf(z1, as[2 * p + 1], s);
        d = fmaf(z0, ad[2 * p], d);
        d = fmaf(z1, ad[2 * p + 1], d);
    }
    es[idx] = s;
    ed[idx] = d;
}

// ---------- CSR build (both graphs, global node ids) ----------
__global__ void zero_int_kernel(int* __restrict__ p, int n) {
    const int i = blockIdx.x * 256 + threadIdx.x;
    if (i < n) p[i] = 0;
}

__global__ void hist2_kernel(const int* __restrict__ ei0, const int* __restrict__ ei1,
                             int* __restrict__ cnt) {
    const int e = blockIdx.x * 256 + threadIdx.x;
    if (e >= NE2) return;
    const int g = e >= N_EDGES;
    const int* ei = g ? ei1 : ei0;
    const int e2 = e - g * N_EDGES;
    atomicAdd(&cnt[g * N_NODES + ei[N_EDGES + e2]], 1);
}

#define SCAN_NB ((NN2 + 1023) / 1024)
__global__ void scan1_kernel(const int* __restrict__ cnt, int* __restrict__ part,
                             int* __restrict__ bsum) {
    __shared__ int s[1024];
    const int t = threadIdx.x;
    const int gid = blockIdx.x * 1024 + t;
    const int v = (gid < NN2) ? cnt[gid] : 0;
    s[t] = v;
    __syncthreads();
    for (int d = 1; d < 1024; d <<= 1) {
        int x = (t >= d) ? s[t - d] : 0;
        __syncthreads();
        s[t] += x;
        __syncthreads();
    }
    part[gid] = s[t] - v;
    if (t == 1023) bsum[blockIdx.x] = s[1023];
}

__global__ void scan2_kernel(int* __restrict__ bsum, int* __restrict__ boff) {
    if (threadIdx.x == 0) {
        int a = 0;
        for (int i = 0; i < SCAN_NB; ++i) { boff[i] = a; a += bsum[i]; }
        boff[SCAN_NB] = a;
    }
}

__global__ void scan3_kernel(const int* __restrict__ part, const int* __restrict__ boff,
                             int* __restrict__ off, int* __restrict__ cursor) {
    const int gid = blockIdx.x * 1024 + threadIdx.x;
    if (gid < NN2) {
        const int o = part[gid] + boff[gid >> 10];
        off[gid] = o;
        cursor[gid] = o;
    }
    if (gid == 0) off[NN2] = boff[SCAN_NB];
}

__global__ void scatter2_kernel(const int* __restrict__ ei0, const int* __restrict__ ei1,
                                int* __restrict__ cursor, int* __restrict__ csr_src) {
    const int e = blockIdx.x * 256 + threadIdx.x;
    if (e >= NE2) return;
    const int g = e >= N_EDGES;
    const int* ei = g ? ei1 : ei0;
    const int e2 = e - g * N_EDGES;
    const int src = ei[e2];
    const int dst = ei[N_EDGES + e2];
    const int slot = atomicAdd(&cursor[g * N_NODES + dst], 1);
    csr_src[slot] = g * N_NODES + src;   // global src id
}

// ---------- fused aggregation (layers 1-2): w + gather + ELU, bf16 out ----------
template <int HF>
__global__ void agg_fused_kernel(const int* __restrict__ off, const int* __restrict__ csr_src,
                                 const float* __restrict__ es, const float* __restrict__ ed,
                                 const unsigned short* __restrict__ z,
                                 unsigned short* __restrict__ outz) {
    constexpr int Fo  = HF / HEADS;
    constexpr int L   = Fo / 2;
    constexpr int EPI = 64 / L;
    const int wid  = (blockIdx.x * blockDim.x + threadIdx.x) >> 6;
    const int lane = threadIdx.x & 63;
    if (wid >= NN2 * HEADS) return;
    const int n = wid / HEADS;
    const int h = wid - n * HEADS;
    const int s0  = off[n];
    const int deg = off[n + 1] - s0;
    const float edn = ed[n * HEADS + h];
    const int eo = lane / L;
    const int fp = lane - eo * L;

    float acc0 = 0.f, acc1 = 0.f, lsum = 0.f;
    for (int base = 0; base < deg; base += 64) {
        const int cnt = min(64, deg - base);
        int my_src = 0;
        float my_w = 0.f;
        if (lane < cnt) {
            my_src = csr_src[s0 + base + lane];
            float v = es[my_src * HEADS + h] + edn;
            v = v > 0.f ? v : 0.2f * v;
            my_w = __expf(v);
        }
#pragma unroll 4
        for (int j = 0; j < cnt; j += EPI) {
            const int jj = j + eo;
            const int   srcj = __shfl(my_src, jj);
            const float wj   = __shfl(my_w, jj);
            if (jj < cnt) {
                lsum += wj;
                const unsigned zz =
                    *(const unsigned*)(z + (size_t)srcj * HF + h * Fo + 2 * fp);
                acc0 = fmaf(wj, bf_lo(zz), acc0);
                acc1 = fmaf(wj, bf_hi(zz), acc1);
            }
        }
    }
#pragma unroll
    for (int d = L; d < 64; d <<= 1) {
        acc0 += __shfl_xor(acc0, d);
        acc1 += __shfl_xor(acc1, d);
        lsum += __shfl_xor(lsum, d);
    }
    if (eo == 0) {
        const float inv = 1.f / (lsum + 1e-16f);
        float o0 = acc0 * inv, o1 = acc1 * inv;
        o0 = o0 > 0.f ? o0 : expm1f(o0);
        o1 = o1 > 0.f ? o1 : expm1f(o1);
        const unsigned p = (unsigned)f2bf(o0) | ((unsigned)f2bf(o1) << 16);
        *(unsigned*)(outz + (size_t)n * HF + h * Fo + 2 * fp) = p;
    }
}

// ---------- layer-3 aggregation fused with sum pooling ----------
// grid-strided: AGG_WAVES waves, head fixed per wave; no node-feature write at all.
#define AGG_BLOCKS 1875
#define AGG_WAVES  (AGG_BLOCKS * 4)          // 7500, divisible by 6
#define AGG_STRIDE (AGG_WAVES / HEADS)       // 1250
__global__ __launch_bounds__(256) void agg_pool_kernel(
        const int* __restrict__ off, const int* __restrict__ csr_src,
        const float* __restrict__ es, const float* __restrict__ ed,
        const unsigned short* __restrict__ z, float* __restrict__ pooled) {
    constexpr int HF = 384, Fo = 64;
    const int gw   = (blockIdx.x * 256 + threadIdx.x) >> 6;
    const int lane = threadIdx.x & 63;
    const int h     = gw % HEADS;       // fixed head for this wave
    const int wslot = gw / HEADS;
    const int eo = lane >> 5;           // 2 edges in parallel (L=32)
    const int fp = lane & 31;

    float p00 = 0.f, p01 = 0.f, p10 = 0.f, p11 = 0.f;   // pooled partials [graph][feat]
    for (int n = wslot; n < NN2; n += AGG_STRIDE) {
        const int s0  = off[n];
        const int deg = off[n + 1] - s0;
        const float edn = ed[n * HEADS + h];
        float acc0 = 0.f, acc1 = 0.f, lsum = 0.f;
        for (int base = 0; base < deg; base += 64) {
            const int cnt = min(64, deg - base);
            int my_src = 0;
            float my_w = 0.f;
            if (lane < cnt) {
                my_src = csr_src[s0 + base + lane];
                float v = es[my_src * HEADS + h] + edn;
                v = v > 0.f ? v : 0.2f * v;
                my_w = __expf(v);
            }
#pragma unroll 4
            for (int j = 0; j < cnt; j += 2) {
                const int jj = j + eo;
                const int   srcj = __shfl(my_src, jj);
                const float wj   = __shfl(my_w, jj);
                if (jj < cnt) {
                    lsum += wj;
                    const unsigned zz =
                        *(const unsigned*)(z + (size_t)srcj * HF + h * Fo + 2 * fp);
                    acc0 = fmaf(wj, bf_lo(zz), acc0);
                    acc1 = fmaf(wj, bf_hi(zz), acc1);
                }
            }
        }
        acc0 += __shfl_xor(acc0, 32);
        acc1 += __shfl_xor(acc1, 32);
        lsum += __shfl_xor(lsum, 32);
        const float inv = 1.f / (lsum + 1e-16f);
        float o0 = acc0 * inv, o1 = acc1 * inv;
        o0 = o0 > 0.f ? o0 : expm1f(o0);
        o1 = o1 > 0.f ? o1 : expm1f(o1);
        if (n < N_NODES) { p00 += o0; p01 += o1; }
        else             { p10 += o0; p11 += o1; }
    }
    if (eo == 0) {
        float* pb = pooled + h * Fo + 2 * fp;
        atomicAdd(pb,           p00);
        atomicAdd(pb + 1,       p01);
        atomicAdd(pb + 384,     p10);
        atomicAdd(pb + 385,     p11);
    }
}

__global__ void zero_pooled_kernel(float* __restrict__ p) {
    const int i = blockIdx.x * 256 + threadIdx.x;
    if (i < 768) p[i] = 0.f;
}

__global__ void final_kernel(const float* __restrict__ pooled, const float* __restrict__ Wd,
                             const float* __restrict__ bd, float* __restrict__ outp) {
    __shared__ float s_ss[256], s_dot[256];
    const int t = threadIdx.x;
    float ss = 0.f, dot = 0.f;
    for (int c = t; c < 768; c += 256) {
        const float v = pooled[c];
        ss  = fmaf(v, v, ss);
        dot = fmaf(v, Wd[c], dot);
    }
    s_ss[t] = ss; s_dot[t] = dot;
    __syncthreads();
    for (int off = 128; off > 0; off >>= 1) {
        if (t < off) { s_ss[t] += s_ss[t + off]; s_dot[t] += s_dot[t + off]; }
        __syncthreads();
    }
    if (t == 0) {
        const float norm = fmaxf(sqrtf(s_ss[0]), 1e-12f);
        outp[0] = s_dot[0] / norm + bd[0];
    }
}

extern "C" void kernel_launch(void* const* d_in, const int* in_sizes, int n_in,
                              void* d_out, int out_size, void* d_ws, size_t ws_size,
                              hipStream_t stream) {
    const float* x_int = (const float*)d_in[0];
    const float* x_nh  = (const float*)d_in[1];
    const int*   ei_int = (const int*)d_in[2];
    const int*   ei_nh  = (const int*)d_in[3];
    const float* W1  = (const float*)d_in[4];
    const float* a1s = (const float*)d_in[5];
    const float* a1d = (const float*)d_in[6];
    const float* W2  = (const float*)d_in[7];
    const float* a2s = (const float*)d_in[8];
    const float* a2d = (const float*)d_in[9];
    const float* W3  = (const float*)d_in[10];
    const float* a3s = (const float*)d_in[11];
    const float* a3d = (const float*)d_in[12];
    const float* Wd  = (const float*)d_in[13];
    const float* bd  = (const float*)d_in[14];
    float* out = (float*)d_out;

    // workspace layout (zbuf 256B-aligned at base)
    unsigned short* zbuf  = (unsigned short*)d_ws;                 // NN2*384 bf16
    unsigned short* hbf_a = zbuf  + (size_t)NN2 * 384;             // NN2*96
    unsigned short* hbf_b = hbf_a + (size_t)NN2 * 96;              // NN2*192
    unsigned short* wt2   = hbf_b + (size_t)NN2 * 192;             // 192*96
    unsigned short* wt3   = wt2   + (size_t)96 * 192;              // 384*192
    float* es    = (float*)(wt3 + (size_t)192 * 384);              // NN2*H
    float* ed    = es + (size_t)NN2 * HEADS;                       // NN2*H
    float* pooled = ed + (size_t)NN2 * HEADS;                      // 768
    int* cnt     = (int*)(pooled + 768);                           // NN2
    int* part    = cnt + NN2;                                      // SCAN_NB*1024
    int* bsum    = part + SCAN_NB * 1024;                          // SCAN_NB
    int* boff    = bsum + SCAN_NB;                                 // SCAN_NB+1
    int* off     = boff + SCAN_NB + 1;                             // NN2+1
    int* cursor  = off + NN2 + 1;                                  // NN2
    int* csr_src = cursor + NN2;                                   // NE2

    zero_pooled_kernel<<<3, 256, 0, stream>>>(pooled);
    convert_wt_kernel<<<(96 * 192 + 255) / 256, 256, 0, stream>>>(W2, wt2, 96, 192);
    convert_wt_kernel<<<(192 * 384 + 255) / 256, 256, 0, stream>>>(W3, wt3, 192, 384);

    // batched CSR over both graphs
    zero_int_kernel<<<(NN2 + 255) / 256, 256, 0, stream>>>(cnt, NN2);
    hist2_kernel<<<(NE2 + 255) / 256, 256, 0, stream>>>(ei_int, ei_nh, cnt);
    scan1_kernel<<<SCAN_NB, 1024, 0, stream>>>(cnt, part, bsum);
    scan2_kernel<<<1, 64, 0, stream>>>(bsum, boff);
    scan3_kernel<<<SCAN_NB, 1024, 0, stream>>>(part, boff, off, cursor);
    scatter2_kernel<<<(NE2 + 255) / 256, 256, 0, stream>>>(ei_int, ei_nh, cursor, csr_src);

    const int mfma_blocks = (NN2 / 16 + 3) / 4;
    const int agg_blocks  = (NN2 * HEADS + 3) / 4;   // 1 wave per (node, head)
    const int prep_blocks = (NN2 * HEADS + 255) / 256;

    // layer 1
    gemm1_kernel<11, 96, 16><<<dim3(NN2 / 16, 2), 64, 0, stream>>>(x_int, x_nh, W1, zbuf);
    prep_kernel<96><<<prep_blocks, 256, 0, stream>>>(zbuf, a1s, a1d, es, ed);
    agg_fused_kernel<96><<<agg_blocks, 256, 0, stream>>>(off, csr_src, es, ed, zbuf, hbf_a);
    // layer 2
    gemm_mfma_kernel<96, 192><<<mfma_blocks, 256, 0, stream>>>(hbf_a, wt2, zbuf);
    prep_kernel<192><<<prep_blocks, 256, 0, stream>>>(zbuf, a2s, a2d, es, ed);
    agg_fused_kernel<192><<<agg_blocks, 256, 0, stream>>>(off, csr_src, es, ed, zbuf, hbf_b);
    // layer 3 (+ fused pooling)
    gemm_mfma_kernel<192, 384><<<mfma_blocks, 256, 0, stream>>>(hbf_b, wt3, zbuf);
    prep_kernel<384><<<prep_blocks, 256, 0, stream>>>(zbuf, a3s, a3d, es, ed);
    agg_pool_kernel<<<AGG_BLOCKS, 256, 0, stream>>>(off, csr_src, es, ed, zbuf, pooled);

    final_kernel<<<1, 256, 0, stream>>>(pooled, Wd, bd, out);
}